// Round 3
// baseline (90.193 us; speedup 1.0000x reference)
//
#include <hip/hip_runtime.h>
#include <hip/hip_bf16.h>

#define BATCH 128
#define NOUT  256
#define MB    8
#define IN    512

#define THREADS 256
#define TI 32            // i-tile per block (2 rows per thread)
#define TB 32            // b-tile per block (2 cols per thread)
#define CH 128           // k-chunk in floats (one chunk per block in main path)
#define CH4 (CH/4)       // 32 float4 per row-chunk
#define ST4 33           // LDS row stride in float4: pair-stride 66*16B -> bank step 8 -> 4-way on w only

__device__ __forceinline__ float fast_exp2(float v) {
#if __has_builtin(__builtin_amdgcn_exp2f)
  return __builtin_amdgcn_exp2f(v);
#else
  return exp2f(v);
#endif
}
__device__ __forceinline__ float fast_rcp(float v) {
#if __has_builtin(__builtin_amdgcn_rcpf)
  return __builtin_amdgcn_rcpf(v);
#else
  return 1.0f / v;
#endif
}

// sum of 4 sigmoids from e_i = exp(-v_i), one rcp:
// sigma(v)=1/(1+e); sum 1/Ai = ((A+B)*CD + (C+D)*AB) / (AB*CD)
__device__ __forceinline__ float sig4(float4 p) {
  float ea = fast_exp2(p.x), eb = fast_exp2(p.y), ec = fast_exp2(p.z), ed = fast_exp2(p.w);
  float A = 1.0f + ea, B = 1.0f + eb, C = 1.0f + ec, D = 1.0f + ed;
  float AB = A * B, CD = C * D;
  float num = fmaf(A + B, CD, (C + D) * AB);
  return num * fast_rcp(AB * CD);
}
__device__ __forceinline__ float4 mul4(float4 a, float4 b) {
  return make_float4(a.x * b.x, a.y * b.y, a.z * b.z, a.w * b.w);
}

// Kernel A: for its (i-tile, b-tile, j-range, k-chunk-range) write
// part[z][i][b] = prod_{j in range} sum_{k in chunks} sigmoid(x*w)
// Main path: jpb=1, kcb=1 -> 1024 blocks, ONE staging phase, 2 barriers total.
__global__ __launch_bounds__(THREADS, 4) void dnm_partial_kernel(
    const float* __restrict__ x, const float* __restrict__ w,
    float* __restrict__ part, int jpb, int kcb)
{
  __shared__ float4 xs4[TI * ST4];
  __shared__ float4 ws4[TB * ST4];

  const int t   = threadIdx.x;
  const int ti2 = t >> 4;     // 0..15 -> i rows i0+2*ti2, +1
  const int tb2 = t & 15;     // 0..15 -> b cols b0+2*tb2, +1
  const int b0  = blockIdx.x * TB;
  const int i0  = blockIdx.y * TI;
  const int kg  = (IN / CH) / kcb;            // k-groups across blocks
  const int j0  = (blockIdx.z / kg) * jpb;
  const int q0  = (blockIdx.z % kg) * kcb;

  const float4* gx = (const float4*)x;
  const float4* gw = (const float4*)w;
  const float NEG_LOG2E = -1.4426950408889634f;

  float p00 = 1.0f, p01 = 1.0f, p10 = 1.0f, p11 = 1.0f;
  for (int jj = 0; jj < jpb; ++jj) {
    const int j = j0 + jj;
    float s00 = 0.0f, s01 = 0.0f, s10 = 0.0f, s11 = 0.0f;
    for (int cc = 0; cc < kcb; ++cc) {
      const int q = q0 + cc;
      __syncthreads();  // previous chunk's reads done (no-op cost in main path)
      // stage 64 rows (32 x + 32 w) x 32 float4; coalesced, x pre-scaled by -log2e
      #pragma unroll
      for (int p = 0; p < (2 * TI * CH4) / THREADS; ++p) {
        int idx = t + p * THREADS;
        int r = idx >> 5, c4 = idx & 31;   // r 0..63, c4 0..31
        if (r < TI) {
          float4 xv = gx[(size_t)((i0 + r) * MB + j) * (IN / 4) + q * CH4 + c4];
          xv.x *= NEG_LOG2E; xv.y *= NEG_LOG2E; xv.z *= NEG_LOG2E; xv.w *= NEG_LOG2E;
          xs4[r * ST4 + c4] = xv;
        } else {
          ws4[(r - TI) * ST4 + c4] =
              gw[(size_t)((b0 + r - TI) * MB + j) * (IN / 4) + q * CH4 + c4];
        }
      }
      __syncthreads();
      const float4* __restrict__ xr0 = &xs4[(2 * ti2)     * ST4];
      const float4* __restrict__ xr1 = &xs4[(2 * ti2 + 1) * ST4];
      const float4* __restrict__ wr0 = &ws4[(2 * tb2)     * ST4];
      const float4* __restrict__ wr1 = &ws4[(2 * tb2 + 1) * ST4];
      #pragma unroll 2
      for (int k4 = 0; k4 < CH4; ++k4) {
        float4 xv0 = xr0[k4], xv1 = xr1[k4];
        float4 wv0 = wr0[k4], wv1 = wr1[k4];
        s00 += sig4(mul4(xv0, wv0));   // 16 independent exp2 per iteration
        s01 += sig4(mul4(xv0, wv1));
        s10 += sig4(mul4(xv1, wv0));
        s11 += sig4(mul4(xv1, wv1));
      }
    }
    p00 *= s00; p01 *= s01; p10 *= s10; p11 *= s11;
  }
  float* dst = part + (size_t)blockIdx.z * (BATCH * NOUT);
  const int i = i0 + 2 * ti2, b = b0 + 2 * tb2;
  dst[(size_t)i * NOUT + b]           = p00;
  dst[(size_t)i * NOUT + b + 1]       = p01;
  dst[(size_t)(i + 1) * NOUT + b]     = p10;
  dst[(size_t)(i + 1) * NOUT + b + 1] = p11;
}

__device__ __forceinline__ float block_sum(float v, float* red) {
  #pragma unroll
  for (int o = 32; o > 0; o >>= 1) v += __shfl_down(v, o, 64);
  int lane = threadIdx.x & 63, wid = threadIdx.x >> 6;
  __syncthreads();
  if (lane == 0) red[wid] = v;
  __syncthreads();
  return red[0] + red[1] + red[2] + red[3];
}

// Kernel B: z[i][b] = prod_j (sum_q part[j*kg+q][i][b]); then row-normalize + standardize (ddof=1)
__global__ __launch_bounds__(256) void dnm_norm_kernel(
    const float* __restrict__ part, float* __restrict__ out, int jg, int kg)
{
  __shared__ float red[4];
  const int i = blockIdx.x;
  const int t = threadIdx.x;
  float z = 1.0f;
  for (int j = 0; j < jg; ++j) {
    float s = 0.0f;
    for (int q = 0; q < kg; ++q)
      s += part[(size_t)(j * kg + q) * (BATCH * NOUT) + (size_t)i * NOUT + t];
    z *= s;
  }
  float S  = block_sum(z, red);
  float zn = z / S;
  float m  = block_sum(zn, red) * (1.0f / NOUT);
  float dv = zn - m;
  float v  = block_sum(dv * dv, red) * (1.0f / (NOUT - 1));
  out[(size_t)i * NOUT + t] = dv / sqrtf(v);
}

extern "C" void kernel_launch(void* const* d_in, const int* in_sizes, int n_in,
                              void* d_out, int out_size, void* d_ws, size_t ws_size,
                              hipStream_t stream) {
  const float* x = (const float*)d_in[0];   // (128, 8, 512)
  const float* w = (const float*)d_in[1];   // (256, 8, 512)
  float* out = (float*)d_out;               // (128, 256)

  const size_t plane = (size_t)BATCH * NOUT * sizeof(float);
  int jg, kg;
  float* part;
  if      (ws_size >= 32 * plane) { jg = 8; kg = 4; part = (float*)d_ws; }  // main path
  else if (ws_size >= 16 * plane) { jg = 8; kg = 2; part = (float*)d_ws; }
  else if (ws_size >=  8 * plane) { jg = 8; kg = 1; part = (float*)d_ws; }
  else if (ws_size >=      plane) { jg = 1; kg = 1; part = (float*)d_ws; }
  else                            { jg = 1; kg = 1; part = out; }           // in-place fallback

  const int jpb = MB / jg;
  const int kcb = (IN / CH) / kg;
  dim3 gridA(NOUT / TB, BATCH / TI, jg * kg);
  dnm_partial_kernel<<<gridA, THREADS, 0, stream>>>(x, w, part, jpb, kcb);
  dnm_norm_kernel<<<dim3(BATCH), 256, 0, stream>>>(part, out, jg, kg);
}